// Round 22
// baseline (103.221 us; speedup 1.0000x reference)
//
#include <hip/hip_runtime.h>
#include <math.h>

typedef short bf16x8 __attribute__((ext_vector_type(8)));
typedef float f32x4  __attribute__((ext_vector_type(4)));

constexpr int   B_    = 4;
constexpr int   N_    = 2048;
constexpr int   INF_  = 256;
constexpr int   OUTF_ = 128;
constexpr float LAMBDA_INIT_ = 0.35550906759096926f;
constexpr float OUT_SCALE_   = 0.64449093240903074f;   // 1 - LAMBDA_INIT
constexpr float EPS_         = 1e-5f;
constexpr float LOG2E_       = 1.44269504088896340736f;

__device__ inline unsigned short f2bf(float x) {
  unsigned u = __float_as_uint(x);
  u += 0x7fffu + ((u >> 16) & 1u);          // round-to-nearest-even
  return (unsigned short)(u >> 16);
}
__device__ inline unsigned pack2(float a, float b) {
  return (unsigned)f2bf(a) | ((unsigned)f2bf(b) << 16);
}

// ---------------- Kernel B: Wh GEMM (4x4 register-blocked) + bf16 T-copy + fused dots
// + folded scalars (block 0, wave 0). r20-passing, unchanged.
__global__ __launch_bounds__(256) void wh_dots_v3(
    const float* __restrict__ h, const float* __restrict__ W,
    const float* __restrict__ alp, const float* __restrict__ arp,
    const float* __restrict__ aln, const float* __restrict__ arn,
    const float* __restrict__ rel_emb,
    const float* __restrict__ a_rel_pos, const float* __restrict__ a_rel_neg,
    const float* __restrict__ ll1, const float* __restrict__ lr1,
    const float* __restrict__ ll2, const float* __restrict__ lr2,
    unsigned short* __restrict__ WhvT,
    float* __restrict__ lposv, float* __restrict__ rposv,
    float* __restrict__ lnegv, float* __restrict__ rnegv,
    float* __restrict__ scal) {
  __shared__ __align__(16) float hT[32][260];
  const int t = threadIdx.x;
  const int row0 = blockIdx.x * 32;
  const int b = row0 >> 11;

  if (blockIdx.x == 0 && t < 64) {
    const int lane = t;
    float p1 = ll1[lane] * lr1[lane];
    float p2 = ll2[lane] * lr2[lane];
    #pragma unroll
    for (int off = 32; off; off >>= 1) { p1 += __shfl_xor(p1, off); p2 += __shfl_xor(p2, off); }
    if (lane == 0) scal[12] = expf(p1) - expf(p2) + LAMBDA_INIT_;
    if (lane < 6) {
      float sp = 0.f, sn = 0.f;
      for (int k = 0; k < 10; ++k) {
        float rv = rel_emb[lane * 10 + k];
        sp += rv * a_rel_pos[k];
        sn += rv * a_rel_neg[k];
      }
      scal[lane]     = sp * LOG2E_;
      scal[6 + lane] = sn * LOG2E_;
    }
  }

  #pragma unroll 8
  for (int i = 0; i < 32; ++i) hT[i][t] = h[(size_t)(row0 + i) * INF_ + t];
  __syncthreads();

  const int rg = t >> 5;
  const int cg = t & 31;
  const int c0 = cg * 4;
  float acc[4][4] = {{0.f,0.f,0.f,0.f},{0.f,0.f,0.f,0.f},{0.f,0.f,0.f,0.f},{0.f,0.f,0.f,0.f}};

  #pragma unroll 2
  for (int k4 = 0; k4 < 64; ++k4) {
    float4 hv[4], wv[4];
    #pragma unroll
    for (int rr = 0; rr < 4; ++rr)
      hv[rr] = *reinterpret_cast<const float4*>(&hT[rg * 4 + rr][k4 * 4]);
    #pragma unroll
    for (int j = 0; j < 4; ++j)
      wv[j] = *reinterpret_cast<const float4*>(&W[(size_t)(k4 * 4 + j) * OUTF_ + c0]);
    #pragma unroll
    for (int rr = 0; rr < 4; ++rr) {
      const float* hp = reinterpret_cast<const float*>(&hv[rr]);
      #pragma unroll
      for (int j = 0; j < 4; ++j) {
        const float* wp = reinterpret_cast<const float*>(&wv[j]);
        acc[rr][0] += hp[j] * wp[0];
        acc[rr][1] += hp[j] * wp[1];
        acc[rr][2] += hp[j] * wp[2];
        acc[rr][3] += hp[j] * wp[3];
      }
    }
  }

  const int n0 = (row0 & 2047) + rg * 4;
  #pragma unroll
  for (int cc = 0; cc < 4; ++cc) {
    uint2 v;
    v.x = pack2(acc[0][cc], acc[1][cc]);
    v.y = pack2(acc[2][cc], acc[3][cc]);
    *reinterpret_cast<uint2*>(WhvT + ((size_t)b * OUTF_ + c0 + cc) * N_ + n0) = v;
  }

  float aL[4], aR[4];
  #pragma unroll
  for (int cc = 0; cc < 4; ++cc) {
    const int c = c0 + cc;
    aL[cc] = (c < 64) ? alp[c] : aln[c - 64];
    aR[cc] = (c < 64) ? arp[c] : arn[c - 64];
  }
  float sl[4], sr2[4];
  #pragma unroll
  for (int rr = 0; rr < 4; ++rr) {
    sl[rr]  = (acc[rr][0] * aL[0] + acc[rr][1] * aL[1]) + (acc[rr][2] * aL[2] + acc[rr][3] * aL[3]);
    sr2[rr] = (acc[rr][0] * aR[0] + acc[rr][1] * aR[1]) + (acc[rr][2] * aR[2] + acc[rr][3] * aR[3]);
  }
  #pragma unroll
  for (int off = 1; off <= 8; off <<= 1) {
    #pragma unroll
    for (int rr = 0; rr < 4; ++rr) {
      sl[rr]  += __shfl_xor(sl[rr],  off);
      sr2[rr] += __shfl_xor(sr2[rr], off);
    }
  }
  if (cg == 0) {
    #pragma unroll
    for (int rr = 0; rr < 4; ++rr) {
      const int node = row0 + rg * 4 + rr;
      lposv[node] = sl[rr]  * LOG2E_;
      rposv[node] = sr2[rr] * LOG2E_;
    }
  } else if (cg == 16) {
    #pragma unroll
    for (int rr = 0; rr < 4; ++rr) {
      const int node = row0 + rg * 4 + rr;
      lnegv[node] = sl[rr]  * LOG2E_;
      rnegv[node] = sr2[rr] * LOG2E_;
    }
  }
}

// ---------------- Kernel D: fused attention + PV(MFMA) + LN + GELU, 8-row blocks ----------------
// 1024 blocks x 512 threads; A-tile 32KB -> 4 blocks/CU (2x r20 occupancy).
// Pass A: wave wv = row wv (running sums only). Pass B: r20-verbatim per-row body over 8 rows.
// Phase 2: r20's MFMA with A-rows 8-15 zeroed per-lane (bl>=8); C kept for kg<2 only.
__global__ __launch_bounds__(512, 8) void fused_attn_pv4(
    const int* __restrict__ adj,
    const float* __restrict__ lposv, const float* __restrict__ rposv,
    const float* __restrict__ lnegv, const float* __restrict__ rnegv,
    const float* __restrict__ scal, const unsigned short* __restrict__ WhvT,
    const float* __restrict__ gamma, const float* __restrict__ beta,
    float* __restrict__ out0, float* __restrict__ out1) {
  __shared__ __align__(16) uint4 A4[8 * 256];                   // 32KB A-tile
  __shared__ float scr[16];                                     // row totals (P:0-7, N:8-15)
  float (*hp)[132] = reinterpret_cast<float (*)[132]>(A4);      // epilogue overlay

  const int t = threadIdx.x;
  const int lane = t & 63;
  const int wv = t >> 6;
  const int bi = blockIdx.x;
  const int b  = bi >> 8;
  const int i0 = (bi & 255) * 8;
  const int flat0 = b * N_ + i0;

  const float lam = scal[12];
  float srcP = -1.0e30f, srcN = -1.0e30f;
  if (lane >= 1 && lane <= 5) { srcP = scal[lane]; srcN = scal[6 + lane]; }
  const int iSrcP = __float_as_int(srcP);
  const int iSrcN = __float_as_int(srcN);

  // ---------------- pass A: wave wv sums row wv (running fp32 sums only) ----------------
  {
    const int row = wv;
    const int flat = flat0 + row;
    const float lP = lposv[flat];
    const float lN = lnegv[flat];
    float sP = 0.f, sN = 0.f;
    #pragma unroll
    for (int c2 = 0; c2 < 8; ++c2) {
      const int j = c2 * 256 + lane * 4;
      int4   av4 = *reinterpret_cast<const int4*>(adj + (size_t)flat * N_ + j);
      float4 rp4 = *reinterpret_cast<const float4*>(rposv + b * N_ + j);
      float4 rn4 = *reinterpret_cast<const float4*>(rnegv + b * N_ + j);
      int   av[4] = {av4.x, av4.y, av4.z, av4.w};
      float rpv[4] = {rp4.x, rp4.y, rp4.z, rp4.w};
      float rnv[4] = {rn4.x, rn4.y, rn4.z, rn4.w};
      #pragma unroll
      for (int q = 0; q < 4; ++q) {
        float rsp = __int_as_float(__builtin_amdgcn_ds_bpermute(av[q] << 2, iSrcP));
        float rsn = __int_as_float(__builtin_amdgcn_ds_bpermute(av[q] << 2, iSrcN));
        float e  = lP + rpv[q] + rsp;
        float en = lN + rnv[q] + rsn;
        e  = fmaxf(e, 0.2f * e);
        en = fmaxf(en, 0.2f * en);
        sP += __builtin_amdgcn_exp2f(e);
        sN += __builtin_amdgcn_exp2f(en);
      }
    }
    #pragma unroll
    for (int off = 32; off; off >>= 1) { sP += __shfl_xor(sP, off); sN += __shfl_xor(sN, off); }
    if (lane == 0) { scr[row] = sP; scr[8 + row] = sN; }
  }
  __syncthreads();

  // ---------------- pass B: per-row body (r20-verbatim), sums from scr ----------------
  const int j0 = t * 4;
  float4 rp4 = *reinterpret_cast<const float4*>(rposv + b * N_ + j0);
  float4 rn4 = *reinterpret_cast<const float4*>(rnegv + b * N_ + j0);
  const float rp[4] = {rp4.x, rp4.y, rp4.z, rp4.w};
  const float rn[4] = {rn4.x, rn4.y, rn4.z, rn4.w};

  const int wchunk = (t >> 1) >> 5;
  const int wloc   = (t >> 1) & 31;

  int4 avN = *reinterpret_cast<const int4*>(adj + (size_t)flat0 * N_ + j0);

  #pragma unroll 4
  for (int r = 0; r < 8; ++r) {
    const int flat = flat0 + r;
    const int4 av4 = avN;
    if (r < 7)
      avN = *reinterpret_cast<const int4*>(adj + (size_t)(flat + 1) * N_ + j0);
    const float lP = lposv[flat];
    const float lN = lnegv[flat];
    int av[4] = {av4.x, av4.y, av4.z, av4.w};

    float p[4], n[4];
    #pragma unroll
    for (int q = 0; q < 4; ++q) {
      float rsp = __int_as_float(__builtin_amdgcn_ds_bpermute(av[q] << 2, iSrcP));
      float rsn = __int_as_float(__builtin_amdgcn_ds_bpermute(av[q] << 2, iSrcN));
      float e  = lP + rp[q] + rsp;
      float en = lN + rn[q] + rsn;
      e  = fmaxf(e, 0.2f * e);                 // leaky (pos scale commutes with log2e)
      en = fmaxf(en, 0.2f * en);
      p[q] = __builtin_amdgcn_exp2f(e);
      n[q] = __builtin_amdgcn_exp2f(en);
    }
    const float s1 = 1.f / scr[r];
    const float s2 = -lam / scr[8 + r];

    float a[4];
    #pragma unroll
    for (int q = 0; q < 4; ++q) a[q] = p[q] * s1 + n[q] * s2;
    float* o1 = out1 + (size_t)flat * N_ + j0;
    *reinterpret_cast<float4*>(o1) = make_float4(a[0], a[1], a[2], a[3]);

    const int uidx = r * 256 + wchunk * 32 + (wloc ^ (r & 7));
    uint2 val;
    val.x = pack2(a[0], a[1]); val.y = pack2(a[2], a[3]);
    reinterpret_cast<uint2*>(A4)[uidx * 2 + (t & 1)] = val;
  }
  __syncthreads();   // A-tile complete

  // ---------------- phase 2: MFMA, A rows 8-15 zeroed per-lane; B reg-prefetched ----------------
  const int bl  = lane & 15;   // A row / B ch within tile
  const int kg  = lane >> 4;   // k-group
  const int ch  = wv * 16 + bl;
  const unsigned short* Bp = WhvT + ((size_t)b * OUTF_ + ch) * N_ + kg * 8;
  f32x4 acc0 = {0.f, 0.f, 0.f, 0.f};   // even chunks
  f32x4 acc1 = {0.f, 0.f, 0.f, 0.f};   // odd chunks
  const int arow = (bl & 7) * 256;     // safe address for all lanes
  const int aswz = bl & 7;
  const bool arow_ok = (bl < 8);
  const bf16x8 azero = {0, 0, 0, 0, 0, 0, 0, 0};

  bf16x8 bBuf[2][8];
  #pragma unroll
  for (int kk = 0; kk < 8; ++kk)
    bBuf[0][kk] = *reinterpret_cast<const bf16x8*>(Bp + kk * 32);

  #pragma unroll
  for (int c = 0; c < 8; ++c) {
    const int cur = c & 1;
    if (c < 7) {
      #pragma unroll
      for (int kk = 0; kk < 8; ++kk)
        bBuf[cur ^ 1][kk] = *reinterpret_cast<const bf16x8*>(Bp + (c + 1) * 256 + kk * 32);
    }
    #pragma unroll
    for (int kk = 0; kk < 8; ++kk) {
      bf16x8 a = *reinterpret_cast<const bf16x8*>(&A4[arow + c * 32 + ((kk * 4 + kg) ^ aswz)]);
      a = arow_ok ? a : azero;
      if (cur == 0) acc0 = __builtin_amdgcn_mfma_f32_16x16x32_bf16(a, bBuf[0][kk], acc0, 0, 0, 0);
      else          acc1 = __builtin_amdgcn_mfma_f32_16x16x32_bf16(a, bBuf[1][kk], acc1, 0, 0, 0);
    }
  }
  __syncthreads();   // all A reads done; overlay hp

  if (kg < 2) {
    #pragma unroll
    for (int q = 0; q < 4; ++q) hp[kg * 4 + q][ch] = acc0[q] + acc1[q];
  }
  __syncthreads();

  if (t < 256) {
    const int row = t >> 5;
    const int c0  = t & 31;
    float v[4], s = 0.f, sq = 0.f;
    #pragma unroll
    for (int e = 0; e < 4; ++e) {
      v[e] = hp[row][c0 + e * 32];
      s += v[e]; sq += v[e] * v[e];
    }
    #pragma unroll
    for (int off = 16; off; off >>= 1) { s += __shfl_xor(s, off); sq += __shfl_xor(sq, off); }
    const float mu  = s  * (1.f / 128.f);
    const float var = sq * (1.f / 128.f) - mu * mu;
    const float inv = rsqrtf(var + EPS_);
    float* orow = out0 + ((size_t)(b * N_ + i0 + row)) * OUTF_;
    #pragma unroll
    for (int e = 0; e < 4; ++e) {
      const int chh = c0 + e * 32;
      float y = (v[e] - mu) * inv * gamma[chh] + beta[chh];
      y *= OUT_SCALE_;
      orow[chh] = 0.5f * y * (1.f + erff(y * 0.70710678118654752f));
    }
  }
}

extern "C" void kernel_launch(void* const* d_in, const int* in_sizes, int n_in,
                              void* d_out, int out_size, void* d_ws, size_t ws_size,
                              hipStream_t stream) {
  (void)in_sizes; (void)n_in; (void)out_size; (void)ws_size;
  const float* h        = (const float*)d_in[0];
  const int*   adj      = (const int*)d_in[1];
  const float* W        = (const float*)d_in[2];
  const float* alp      = (const float*)d_in[3];
  const float* arp      = (const float*)d_in[4];
  const float* aln      = (const float*)d_in[5];
  const float* arn      = (const float*)d_in[6];
  const float* rel_emb  = (const float*)d_in[7];
  const float* a_rel_p  = (const float*)d_in[8];
  const float* a_rel_n  = (const float*)d_in[9];
  const float* ll1      = (const float*)d_in[10];
  const float* lr1      = (const float*)d_in[11];
  const float* ll2      = (const float*)d_in[12];
  const float* lr2      = (const float*)d_in[13];
  const float* gamma    = (const float*)d_in[14];
  const float* beta     = (const float*)d_in[15];

  float* out0 = (float*)d_out;                          // gelu(h'): B*N*OUTF
  float* out1 = out0 + (size_t)B_ * N_ * OUTF_;         // attention: B*N*N

  float* ws    = (float*)d_ws;
  float* scal  = ws;                    // 32 floats
  float* lposv = ws + 32;               // B*N
  float* rposv = lposv + B_ * N_;
  float* lnegv = rposv + B_ * N_;
  float* rnegv = lnegv + B_ * N_;
  unsigned short* WhvT = (unsigned short*)(rnegv + B_ * N_);   // [B][OUTF][N] bf16

  wh_dots_v3<<<(B_ * N_) / 32, 256, 0, stream>>>(h, W, alp, arp, aln, arn,
                                                 rel_emb, a_rel_p, a_rel_n,
                                                 ll1, lr1, ll2, lr2,
                                                 WhvT, lposv, rposv, lnegv, rnegv, scal);
  fused_attn_pv4<<<B_ * (N_ / 8), 512, 0, stream>>>(adj, lposv, rposv, lnegv, rnegv,
                                                    scal, WhvT, gamma, beta, out0, out1);
}

// Round 23
// 79.355 us; speedup vs baseline: 1.3008x; 1.3008x over previous
//
#include <hip/hip_runtime.h>
#include <math.h>

typedef short bf16x8 __attribute__((ext_vector_type(8)));
typedef float f32x4  __attribute__((ext_vector_type(4)));

constexpr int   B_    = 4;
constexpr int   N_    = 2048;
constexpr int   INF_  = 256;
constexpr int   OUTF_ = 128;
constexpr float LAMBDA_INIT_ = 0.35550906759096926f;
constexpr float OUT_SCALE_   = 0.64449093240903074f;   // 1 - LAMBDA_INIT
constexpr float EPS_         = 1e-5f;
constexpr float LOG2E_       = 1.44269504088896340736f;

__device__ inline unsigned short f2bf(float x) {
  unsigned u = __float_as_uint(x);
  u += 0x7fffu + ((u >> 16) & 1u);          // round-to-nearest-even
  return (unsigned short)(u >> 16);
}
__device__ inline unsigned pack2(float a, float b) {
  return (unsigned)f2bf(a) | ((unsigned)f2bf(b) << 16);
}

// ---------------- Kernel B: Wh GEMM (4x4 register-blocked) + bf16 T-copy + fused dots
// + folded scalars (block 0, wave 0). r20-passing, byte-identical restore.
__global__ __launch_bounds__(256) void wh_dots_v3(
    const float* __restrict__ h, const float* __restrict__ W,
    const float* __restrict__ alp, const float* __restrict__ arp,
    const float* __restrict__ aln, const float* __restrict__ arn,
    const float* __restrict__ rel_emb,
    const float* __restrict__ a_rel_pos, const float* __restrict__ a_rel_neg,
    const float* __restrict__ ll1, const float* __restrict__ lr1,
    const float* __restrict__ ll2, const float* __restrict__ lr2,
    unsigned short* __restrict__ WhvT,
    float* __restrict__ lposv, float* __restrict__ rposv,
    float* __restrict__ lnegv, float* __restrict__ rnegv,
    float* __restrict__ scal) {
  __shared__ __align__(16) float hT[32][260];
  const int t = threadIdx.x;
  const int row0 = blockIdx.x * 32;
  const int b = row0 >> 11;

  if (blockIdx.x == 0 && t < 64) {
    const int lane = t;
    float p1 = ll1[lane] * lr1[lane];
    float p2 = ll2[lane] * lr2[lane];
    #pragma unroll
    for (int off = 32; off; off >>= 1) { p1 += __shfl_xor(p1, off); p2 += __shfl_xor(p2, off); }
    if (lane == 0) scal[12] = expf(p1) - expf(p2) + LAMBDA_INIT_;
    if (lane < 6) {
      float sp = 0.f, sn = 0.f;
      for (int k = 0; k < 10; ++k) {
        float rv = rel_emb[lane * 10 + k];
        sp += rv * a_rel_pos[k];
        sn += rv * a_rel_neg[k];
      }
      scal[lane]     = sp * LOG2E_;
      scal[6 + lane] = sn * LOG2E_;
    }
  }

  #pragma unroll 8
  for (int i = 0; i < 32; ++i) hT[i][t] = h[(size_t)(row0 + i) * INF_ + t];
  __syncthreads();

  const int rg = t >> 5;
  const int cg = t & 31;
  const int c0 = cg * 4;
  float acc[4][4] = {{0.f,0.f,0.f,0.f},{0.f,0.f,0.f,0.f},{0.f,0.f,0.f,0.f},{0.f,0.f,0.f,0.f}};

  #pragma unroll 2
  for (int k4 = 0; k4 < 64; ++k4) {
    float4 hv[4], wv[4];
    #pragma unroll
    for (int rr = 0; rr < 4; ++rr)
      hv[rr] = *reinterpret_cast<const float4*>(&hT[rg * 4 + rr][k4 * 4]);
    #pragma unroll
    for (int j = 0; j < 4; ++j)
      wv[j] = *reinterpret_cast<const float4*>(&W[(size_t)(k4 * 4 + j) * OUTF_ + c0]);
    #pragma unroll
    for (int rr = 0; rr < 4; ++rr) {
      const float* hp = reinterpret_cast<const float*>(&hv[rr]);
      #pragma unroll
      for (int j = 0; j < 4; ++j) {
        const float* wp = reinterpret_cast<const float*>(&wv[j]);
        acc[rr][0] += hp[j] * wp[0];
        acc[rr][1] += hp[j] * wp[1];
        acc[rr][2] += hp[j] * wp[2];
        acc[rr][3] += hp[j] * wp[3];
      }
    }
  }

  const int n0 = (row0 & 2047) + rg * 4;
  #pragma unroll
  for (int cc = 0; cc < 4; ++cc) {
    uint2 v;
    v.x = pack2(acc[0][cc], acc[1][cc]);
    v.y = pack2(acc[2][cc], acc[3][cc]);
    *reinterpret_cast<uint2*>(WhvT + ((size_t)b * OUTF_ + c0 + cc) * N_ + n0) = v;
  }

  float aL[4], aR[4];
  #pragma unroll
  for (int cc = 0; cc < 4; ++cc) {
    const int c = c0 + cc;
    aL[cc] = (c < 64) ? alp[c] : aln[c - 64];
    aR[cc] = (c < 64) ? arp[c] : arn[c - 64];
  }
  float sl[4], sr2[4];
  #pragma unroll
  for (int rr = 0; rr < 4; ++rr) {
    sl[rr]  = (acc[rr][0] * aL[0] + acc[rr][1] * aL[1]) + (acc[rr][2] * aL[2] + acc[rr][3] * aL[3]);
    sr2[rr] = (acc[rr][0] * aR[0] + acc[rr][1] * aR[1]) + (acc[rr][2] * aR[2] + acc[rr][3] * aR[3]);
  }
  #pragma unroll
  for (int off = 1; off <= 8; off <<= 1) {
    #pragma unroll
    for (int rr = 0; rr < 4; ++rr) {
      sl[rr]  += __shfl_xor(sl[rr],  off);
      sr2[rr] += __shfl_xor(sr2[rr], off);
    }
  }
  if (cg == 0) {
    #pragma unroll
    for (int rr = 0; rr < 4; ++rr) {
      const int node = row0 + rg * 4 + rr;
      lposv[node] = sl[rr]  * LOG2E_;
      rposv[node] = sr2[rr] * LOG2E_;
    }
  } else if (cg == 16) {
    #pragma unroll
    for (int rr = 0; rr < 4; ++rr) {
      const int node = row0 + rg * 4 + rr;
      lnegv[node] = sl[rr]  * LOG2E_;
      rnegv[node] = sr2[rr] * LOG2E_;
    }
  }
}

// ---------------- Kernel D: fused attention + PV(MFMA) + LN + GELU, two-pass phase 1 ----------------
// r20-passing, byte-identical restore. 512 blocks x 512 threads.
__global__ __launch_bounds__(512, 4) void fused_attn_pv2(
    const int* __restrict__ adj,
    const float* __restrict__ lposv, const float* __restrict__ rposv,
    const float* __restrict__ lnegv, const float* __restrict__ rnegv,
    const float* __restrict__ scal, const unsigned short* __restrict__ WhvT,
    const float* __restrict__ gamma, const float* __restrict__ beta,
    float* __restrict__ out0, float* __restrict__ out1) {
  __shared__ __align__(16) uint4 A4[16 * 256];                  // 64KB A-tile
  __shared__ float scr[32];                                     // row totals (P:0-15, N:16-31)
  float (*hp)[132] = reinterpret_cast<float (*)[132]>(A4);      // epilogue overlay

  const int t = threadIdx.x;
  const int lane = t & 63;
  const int wv = t >> 6;
  const int bi = blockIdx.x;
  const int b  = bi >> 7;
  const int i0 = (bi & 127) * 16;
  const int flat0 = b * N_ + i0;

  const float lam = scal[12];
  float srcP = -1.0e30f, srcN = -1.0e30f;
  if (lane >= 1 && lane <= 5) { srcP = scal[lane]; srcN = scal[6 + lane]; }
  const int iSrcP = __float_as_int(srcP);
  const int iSrcN = __float_as_int(srcN);

  // ---------------- pass A: wave-local row sums (no per-element storage) ----------------
  #pragma unroll
  for (int rr = 0; rr < 2; ++rr) {
    const int row = wv * 2 + rr;
    const int flat = flat0 + row;
    const float lP = lposv[flat];
    const float lN = lnegv[flat];
    float sP = 0.f, sN = 0.f;
    #pragma unroll
    for (int c2 = 0; c2 < 8; ++c2) {
      const int j = c2 * 256 + lane * 4;
      int4   av4 = *reinterpret_cast<const int4*>(adj + (size_t)flat * N_ + j);
      float4 rp4 = *reinterpret_cast<const float4*>(rposv + b * N_ + j);
      float4 rn4 = *reinterpret_cast<const float4*>(rnegv + b * N_ + j);
      int   av[4] = {av4.x, av4.y, av4.z, av4.w};
      float rpv[4] = {rp4.x, rp4.y, rp4.z, rp4.w};
      float rnv[4] = {rn4.x, rn4.y, rn4.z, rn4.w};
      #pragma unroll
      for (int q = 0; q < 4; ++q) {
        float rsp = __int_as_float(__builtin_amdgcn_ds_bpermute(av[q] << 2, iSrcP));
        float rsn = __int_as_float(__builtin_amdgcn_ds_bpermute(av[q] << 2, iSrcN));
        float e  = lP + rpv[q] + rsp;
        float en = lN + rnv[q] + rsn;
        e  = fmaxf(e, 0.2f * e);
        en = fmaxf(en, 0.2f * en);
        sP += __builtin_amdgcn_exp2f(e);
        sN += __builtin_amdgcn_exp2f(en);
      }
    }
    #pragma unroll
    for (int off = 32; off; off >>= 1) { sP += __shfl_xor(sP, off); sN += __shfl_xor(sN, off); }
    if (lane == 0) { scr[row] = sP; scr[16 + row] = sN; }
  }
  __syncthreads();

  // ---------------- pass B: per-row body, sums from scr ----------------
  const int j0 = t * 4;
  float4 rp4 = *reinterpret_cast<const float4*>(rposv + b * N_ + j0);
  float4 rn4 = *reinterpret_cast<const float4*>(rnegv + b * N_ + j0);
  const float rp[4] = {rp4.x, rp4.y, rp4.z, rp4.w};
  const float rn[4] = {rn4.x, rn4.y, rn4.z, rn4.w};

  const int wchunk = (t >> 1) >> 5;
  const int wloc   = (t >> 1) & 31;

  int4 avN = *reinterpret_cast<const int4*>(adj + (size_t)flat0 * N_ + j0);

  #pragma unroll 4
  for (int r = 0; r < 16; ++r) {
    const int flat = flat0 + r;
    const int4 av4 = avN;
    if (r < 15)
      avN = *reinterpret_cast<const int4*>(adj + (size_t)(flat + 1) * N_ + j0);
    const float lP = lposv[flat];
    const float lN = lnegv[flat];
    int av[4] = {av4.x, av4.y, av4.z, av4.w};

    float p[4], n[4];
    #pragma unroll
    for (int q = 0; q < 4; ++q) {
      float rsp = __int_as_float(__builtin_amdgcn_ds_bpermute(av[q] << 2, iSrcP));
      float rsn = __int_as_float(__builtin_amdgcn_ds_bpermute(av[q] << 2, iSrcN));
      float e  = lP + rp[q] + rsp;
      float en = lN + rn[q] + rsn;
      e  = fmaxf(e, 0.2f * e);                 // leaky (pos scale commutes with log2e)
      en = fmaxf(en, 0.2f * en);
      p[q] = __builtin_amdgcn_exp2f(e);
      n[q] = __builtin_amdgcn_exp2f(en);
    }
    const float s1 = 1.f / scr[r];
    const float s2 = -lam / scr[16 + r];

    float a[4];
    #pragma unroll
    for (int q = 0; q < 4; ++q) a[q] = p[q] * s1 + n[q] * s2;
    float* o1 = out1 + (size_t)flat * N_ + j0;
    *reinterpret_cast<float4*>(o1) = make_float4(a[0], a[1], a[2], a[3]);

    const int uidx = r * 256 + wchunk * 32 + (wloc ^ (r & 7));
    uint2 val;
    val.x = pack2(a[0], a[1]); val.y = pack2(a[2], a[3]);
    reinterpret_cast<uint2*>(A4)[uidx * 2 + (t & 1)] = val;
  }
  __syncthreads();   // A-tile complete

  // ---------------- phase 2: MFMA over full K, A from LDS, B reg-prefetched ----------------
  const int bl  = lane & 15;   // A row / B ch within tile
  const int kg  = lane >> 4;   // k-group
  const int ch  = wv * 16 + bl;
  const unsigned short* Bp = WhvT + ((size_t)b * OUTF_ + ch) * N_ + kg * 8;
  f32x4 acc0 = {0.f, 0.f, 0.f, 0.f};   // even chunks
  f32x4 acc1 = {0.f, 0.f, 0.f, 0.f};   // odd chunks
  const int arow = bl * 256;
  const int aswz = bl & 7;

  bf16x8 bBuf[2][8];
  #pragma unroll
  for (int kk = 0; kk < 8; ++kk)
    bBuf[0][kk] = *reinterpret_cast<const bf16x8*>(Bp + kk * 32);

  #pragma unroll
  for (int c = 0; c < 8; ++c) {
    const int cur = c & 1;
    if (c < 7) {
      #pragma unroll
      for (int kk = 0; kk < 8; ++kk)
        bBuf[cur ^ 1][kk] = *reinterpret_cast<const bf16x8*>(Bp + (c + 1) * 256 + kk * 32);
    }
    #pragma unroll
    for (int kk = 0; kk < 8; ++kk) {
      bf16x8 a = *reinterpret_cast<const bf16x8*>(&A4[arow + c * 32 + ((kk * 4 + kg) ^ aswz)]);
      if (cur == 0) acc0 = __builtin_amdgcn_mfma_f32_16x16x32_bf16(a, bBuf[0][kk], acc0, 0, 0, 0);
      else          acc1 = __builtin_amdgcn_mfma_f32_16x16x32_bf16(a, bBuf[1][kk], acc1, 0, 0, 0);
    }
  }
  __syncthreads();   // all A reads done; overlay hp

  #pragma unroll
  for (int q = 0; q < 4; ++q) hp[kg * 4 + q][ch] = acc0[q] + acc1[q];
  __syncthreads();

  const int row = t >> 5;
  const int c0  = t & 31;
  float v[4], s = 0.f, sq = 0.f;
  #pragma unroll
  for (int e = 0; e < 4; ++e) {
    v[e] = hp[row][c0 + e * 32];
    s += v[e]; sq += v[e] * v[e];
  }
  #pragma unroll
  for (int off = 16; off; off >>= 1) { s += __shfl_xor(s, off); sq += __shfl_xor(sq, off); }
  const float mu  = s  * (1.f / 128.f);
  const float var = sq * (1.f / 128.f) - mu * mu;
  const float inv = rsqrtf(var + EPS_);
  float* orow = out0 + ((size_t)(b * N_ + i0 + row)) * OUTF_;
  #pragma unroll
  for (int e = 0; e < 4; ++e) {
    const int chh = c0 + e * 32;
    float y = (v[e] - mu) * inv * gamma[chh] + beta[chh];
    y *= OUT_SCALE_;
    orow[chh] = 0.5f * y * (1.f + erff(y * 0.70710678118654752f));
  }
}

extern "C" void kernel_launch(void* const* d_in, const int* in_sizes, int n_in,
                              void* d_out, int out_size, void* d_ws, size_t ws_size,
                              hipStream_t stream) {
  (void)in_sizes; (void)n_in; (void)out_size; (void)ws_size;
  const float* h        = (const float*)d_in[0];
  const int*   adj      = (const int*)d_in[1];
  const float* W        = (const float*)d_in[2];
  const float* alp      = (const float*)d_in[3];
  const float* arp      = (const float*)d_in[4];
  const float* aln      = (const float*)d_in[5];
  const float* arn      = (const float*)d_in[6];
  const float* rel_emb  = (const float*)d_in[7];
  const float* a_rel_p  = (const float*)d_in[8];
  const float* a_rel_n  = (const float*)d_in[9];
  const float* ll1      = (const float*)d_in[10];
  const float* lr1      = (const float*)d_in[11];
  const float* ll2      = (const float*)d_in[12];
  const float* lr2      = (const float*)d_in[13];
  const float* gamma    = (const float*)d_in[14];
  const float* beta     = (const float*)d_in[15];

  float* out0 = (float*)d_out;                          // gelu(h'): B*N*OUTF
  float* out1 = out0 + (size_t)B_ * N_ * OUTF_;         // attention: B*N*N

  float* ws    = (float*)d_ws;
  float* scal  = ws;                    // 32 floats
  float* lposv = ws + 32;               // B*N
  float* rposv = lposv + B_ * N_;
  float* lnegv = rposv + B_ * N_;
  float* rnegv = lnegv + B_ * N_;
  unsigned short* WhvT = (unsigned short*)(rnegv + B_ * N_);   // [B][OUTF][N] bf16

  wh_dots_v3<<<(B_ * N_) / 32, 256, 0, stream>>>(h, W, alp, arp, aln, arn,
                                                 rel_emb, a_rel_p, a_rel_n,
                                                 ll1, lr1, ll2, lr2,
                                                 WhvT, lposv, rposv, lnegv, rnegv, scal);
  fused_attn_pv2<<<B_ * (N_ / 16), 512, 0, stream>>>(adj, lposv, rposv, lnegv, rnegv,
                                                     scal, WhvT, gamma, beta, out0, out1);
}

// Round 24
// 78.156 us; speedup vs baseline: 1.3207x; 1.0153x over previous
//
#include <hip/hip_runtime.h>
#include <math.h>

typedef short bf16x8 __attribute__((ext_vector_type(8)));
typedef float f32x4  __attribute__((ext_vector_type(4)));

constexpr int   B_    = 4;
constexpr int   N_    = 2048;
constexpr int   INF_  = 256;
constexpr int   OUTF_ = 128;
constexpr float LAMBDA_INIT_ = 0.35550906759096926f;
constexpr float OUT_SCALE_   = 0.64449093240903074f;   // 1 - LAMBDA_INIT
constexpr float EPS_         = 1e-5f;
constexpr float LOG2E_       = 1.44269504088896340736f;

__device__ inline unsigned short f2bf(float x) {
  unsigned u = __float_as_uint(x);
  u += 0x7fffu + ((u >> 16) & 1u);          // round-to-nearest-even
  return (unsigned short)(u >> 16);
}
__device__ inline unsigned pack2(float a, float b) {
  return (unsigned)f2bf(a) | ((unsigned)f2bf(b) << 16);
}

// ---------------- Kernel B: Wh GEMM (4x4 register-blocked) + bf16 T-copy + fused dots
// + folded scalars (block 0, wave 0). r20/r23-passing, unchanged.
__global__ __launch_bounds__(256) void wh_dots_v3(
    const float* __restrict__ h, const float* __restrict__ W,
    const float* __restrict__ alp, const float* __restrict__ arp,
    const float* __restrict__ aln, const float* __restrict__ arn,
    const float* __restrict__ rel_emb,
    const float* __restrict__ a_rel_pos, const float* __restrict__ a_rel_neg,
    const float* __restrict__ ll1, const float* __restrict__ lr1,
    const float* __restrict__ ll2, const float* __restrict__ lr2,
    unsigned short* __restrict__ WhvT,
    float* __restrict__ lposv, float* __restrict__ rposv,
    float* __restrict__ lnegv, float* __restrict__ rnegv,
    float* __restrict__ scal) {
  __shared__ __align__(16) float hT[32][260];
  const int t = threadIdx.x;
  const int row0 = blockIdx.x * 32;
  const int b = row0 >> 11;

  if (blockIdx.x == 0 && t < 64) {
    const int lane = t;
    float p1 = ll1[lane] * lr1[lane];
    float p2 = ll2[lane] * lr2[lane];
    #pragma unroll
    for (int off = 32; off; off >>= 1) { p1 += __shfl_xor(p1, off); p2 += __shfl_xor(p2, off); }
    if (lane == 0) scal[12] = expf(p1) - expf(p2) + LAMBDA_INIT_;
    if (lane < 6) {
      float sp = 0.f, sn = 0.f;
      for (int k = 0; k < 10; ++k) {
        float rv = rel_emb[lane * 10 + k];
        sp += rv * a_rel_pos[k];
        sn += rv * a_rel_neg[k];
      }
      scal[lane]     = sp * LOG2E_;
      scal[6 + lane] = sn * LOG2E_;
    }
  }

  #pragma unroll 8
  for (int i = 0; i < 32; ++i) hT[i][t] = h[(size_t)(row0 + i) * INF_ + t];
  __syncthreads();

  const int rg = t >> 5;
  const int cg = t & 31;
  const int c0 = cg * 4;
  float acc[4][4] = {{0.f,0.f,0.f,0.f},{0.f,0.f,0.f,0.f},{0.f,0.f,0.f,0.f},{0.f,0.f,0.f,0.f}};

  #pragma unroll 2
  for (int k4 = 0; k4 < 64; ++k4) {
    float4 hv[4], wv[4];
    #pragma unroll
    for (int rr = 0; rr < 4; ++rr)
      hv[rr] = *reinterpret_cast<const float4*>(&hT[rg * 4 + rr][k4 * 4]);
    #pragma unroll
    for (int j = 0; j < 4; ++j)
      wv[j] = *reinterpret_cast<const float4*>(&W[(size_t)(k4 * 4 + j) * OUTF_ + c0]);
    #pragma unroll
    for (int rr = 0; rr < 4; ++rr) {
      const float* hp = reinterpret_cast<const float*>(&hv[rr]);
      #pragma unroll
      for (int j = 0; j < 4; ++j) {
        const float* wp = reinterpret_cast<const float*>(&wv[j]);
        acc[rr][0] += hp[j] * wp[0];
        acc[rr][1] += hp[j] * wp[1];
        acc[rr][2] += hp[j] * wp[2];
        acc[rr][3] += hp[j] * wp[3];
      }
    }
  }

  const int n0 = (row0 & 2047) + rg * 4;
  #pragma unroll
  for (int cc = 0; cc < 4; ++cc) {
    uint2 v;
    v.x = pack2(acc[0][cc], acc[1][cc]);
    v.y = pack2(acc[2][cc], acc[3][cc]);
    *reinterpret_cast<uint2*>(WhvT + ((size_t)b * OUTF_ + c0 + cc) * N_ + n0) = v;
  }

  float aL[4], aR[4];
  #pragma unroll
  for (int cc = 0; cc < 4; ++cc) {
    const int c = c0 + cc;
    aL[cc] = (c < 64) ? alp[c] : aln[c - 64];
    aR[cc] = (c < 64) ? arp[c] : arn[c - 64];
  }
  float sl[4], sr2[4];
  #pragma unroll
  for (int rr = 0; rr < 4; ++rr) {
    sl[rr]  = (acc[rr][0] * aL[0] + acc[rr][1] * aL[1]) + (acc[rr][2] * aL[2] + acc[rr][3] * aL[3]);
    sr2[rr] = (acc[rr][0] * aR[0] + acc[rr][1] * aR[1]) + (acc[rr][2] * aR[2] + acc[rr][3] * aR[3]);
  }
  #pragma unroll
  for (int off = 1; off <= 8; off <<= 1) {
    #pragma unroll
    for (int rr = 0; rr < 4; ++rr) {
      sl[rr]  += __shfl_xor(sl[rr],  off);
      sr2[rr] += __shfl_xor(sr2[rr], off);
    }
  }
  if (cg == 0) {
    #pragma unroll
    for (int rr = 0; rr < 4; ++rr) {
      const int node = row0 + rg * 4 + rr;
      lposv[node] = sl[rr]  * LOG2E_;
      rposv[node] = sr2[rr] * LOG2E_;
    }
  } else if (cg == 16) {
    #pragma unroll
    for (int rr = 0; rr < 4; ++rr) {
      const int node = row0 + rg * 4 + rr;
      lnegv[node] = sl[rr]  * LOG2E_;
      rnegv[node] = sr2[rr] * LOG2E_;
    }
  }
}

// ---------------- Kernel D: fused attention + PV(MFMA) + LN + GELU, MLP-batched loads ----------------
// r23 structure; only the load schedule changes: pass A batches 12x16B loads per half-row,
// pass B prefetches 4 rows of adj per group. Same element order -> bit-identical results.
__global__ __launch_bounds__(512, 4) void fused_attn_pv5(
    const int* __restrict__ adj,
    const float* __restrict__ lposv, const float* __restrict__ rposv,
    const float* __restrict__ lnegv, const float* __restrict__ rnegv,
    const float* __restrict__ scal, const unsigned short* __restrict__ WhvT,
    const float* __restrict__ gamma, const float* __restrict__ beta,
    float* __restrict__ out0, float* __restrict__ out1) {
  __shared__ __align__(16) uint4 A4[16 * 256];                  // 64KB A-tile
  __shared__ float scr[32];                                     // row totals (P:0-15, N:16-31)
  float (*hp)[132] = reinterpret_cast<float (*)[132]>(A4);      // epilogue overlay

  const int t = threadIdx.x;
  const int lane = t & 63;
  const int wv = t >> 6;
  const int bi = blockIdx.x;
  const int b  = bi >> 7;
  const int i0 = (bi & 127) * 16;
  const int flat0 = b * N_ + i0;

  const float lam = scal[12];
  float srcP = -1.0e30f, srcN = -1.0e30f;
  if (lane >= 1 && lane <= 5) { srcP = scal[lane]; srcN = scal[6 + lane]; }
  const int iSrcP = __float_as_int(srcP);
  const int iSrcN = __float_as_int(srcN);

  // ---------------- pass A: wave-local row sums; 12 loads in flight per batch ----------------
  #pragma unroll
  for (int rr = 0; rr < 2; ++rr) {
    const int row = wv * 2 + rr;
    const int flat = flat0 + row;
    const float lP = lposv[flat];
    const float lN = lnegv[flat];
    float sP = 0.f, sN = 0.f;
    #pragma unroll
    for (int half = 0; half < 2; ++half) {
      int4   av4[4];
      float4 rp4[4], rn4[4];
      #pragma unroll
      for (int c = 0; c < 4; ++c) {
        const int j = (half * 4 + c) * 256 + lane * 4;
        av4[c] = *reinterpret_cast<const int4*>(adj + (size_t)flat * N_ + j);
        rp4[c] = *reinterpret_cast<const float4*>(rposv + b * N_ + j);
        rn4[c] = *reinterpret_cast<const float4*>(rnegv + b * N_ + j);
      }
      #pragma unroll
      for (int c = 0; c < 4; ++c) {
        int   av[4] = {av4[c].x, av4[c].y, av4[c].z, av4[c].w};
        float rpv[4] = {rp4[c].x, rp4[c].y, rp4[c].z, rp4[c].w};
        float rnv[4] = {rn4[c].x, rn4[c].y, rn4[c].z, rn4[c].w};
        #pragma unroll
        for (int q = 0; q < 4; ++q) {
          float rsp = __int_as_float(__builtin_amdgcn_ds_bpermute(av[q] << 2, iSrcP));
          float rsn = __int_as_float(__builtin_amdgcn_ds_bpermute(av[q] << 2, iSrcN));
          float e  = lP + rpv[q] + rsp;
          float en = lN + rnv[q] + rsn;
          e  = fmaxf(e, 0.2f * e);
          en = fmaxf(en, 0.2f * en);
          sP += __builtin_amdgcn_exp2f(e);
          sN += __builtin_amdgcn_exp2f(en);
        }
      }
    }
    #pragma unroll
    for (int off = 32; off; off >>= 1) { sP += __shfl_xor(sP, off); sN += __shfl_xor(sN, off); }
    if (lane == 0) { scr[row] = sP; scr[16 + row] = sN; }
  }
  __syncthreads();

  // ---------------- pass B: per-row body, 4-row adj prefetch groups ----------------
  const int j0 = t * 4;
  float4 rpb4 = *reinterpret_cast<const float4*>(rposv + b * N_ + j0);
  float4 rnb4 = *reinterpret_cast<const float4*>(rnegv + b * N_ + j0);
  const float rp[4] = {rpb4.x, rpb4.y, rpb4.z, rpb4.w};
  const float rn[4] = {rnb4.x, rnb4.y, rnb4.z, rnb4.w};

  const int wchunk = (t >> 1) >> 5;
  const int wloc   = (t >> 1) & 31;

  #pragma unroll
  for (int g = 0; g < 4; ++g) {
    int4 avg[4];
    #pragma unroll
    for (int rr2 = 0; rr2 < 4; ++rr2)
      avg[rr2] = *reinterpret_cast<const int4*>(adj + (size_t)(flat0 + g * 4 + rr2) * N_ + j0);
    #pragma unroll
    for (int rr2 = 0; rr2 < 4; ++rr2) {
      const int r = g * 4 + rr2;
      const int flat = flat0 + r;
      const float lP = lposv[flat];
      const float lN = lnegv[flat];
      int av[4] = {avg[rr2].x, avg[rr2].y, avg[rr2].z, avg[rr2].w};

      float p[4], n[4];
      #pragma unroll
      for (int q = 0; q < 4; ++q) {
        float rsp = __int_as_float(__builtin_amdgcn_ds_bpermute(av[q] << 2, iSrcP));
        float rsn = __int_as_float(__builtin_amdgcn_ds_bpermute(av[q] << 2, iSrcN));
        float e  = lP + rp[q] + rsp;
        float en = lN + rn[q] + rsn;
        e  = fmaxf(e, 0.2f * e);                 // leaky (pos scale commutes with log2e)
        en = fmaxf(en, 0.2f * en);
        p[q] = __builtin_amdgcn_exp2f(e);
        n[q] = __builtin_amdgcn_exp2f(en);
      }
      const float s1 = 1.f / scr[r];
      const float s2 = -lam / scr[16 + r];

      float a[4];
      #pragma unroll
      for (int q = 0; q < 4; ++q) a[q] = p[q] * s1 + n[q] * s2;
      float* o1 = out1 + (size_t)flat * N_ + j0;
      *reinterpret_cast<float4*>(o1) = make_float4(a[0], a[1], a[2], a[3]);

      const int uidx = r * 256 + wchunk * 32 + (wloc ^ (r & 7));
      uint2 val;
      val.x = pack2(a[0], a[1]); val.y = pack2(a[2], a[3]);
      reinterpret_cast<uint2*>(A4)[uidx * 2 + (t & 1)] = val;
    }
  }
  __syncthreads();   // A-tile complete

  // ---------------- phase 2: MFMA over full K, A from LDS, B reg-prefetched (r23-verbatim) ----------------
  const int bl  = lane & 15;   // A row / B ch within tile
  const int kg  = lane >> 4;   // k-group
  const int ch  = wv * 16 + bl;
  const unsigned short* Bp = WhvT + ((size_t)b * OUTF_ + ch) * N_ + kg * 8;
  f32x4 acc0 = {0.f, 0.f, 0.f, 0.f};   // even chunks
  f32x4 acc1 = {0.f, 0.f, 0.f, 0.f};   // odd chunks
  const int arow = bl * 256;
  const int aswz = bl & 7;

  bf16x8 bBuf[2][8];
  #pragma unroll
  for (int kk = 0; kk < 8; ++kk)
    bBuf[0][kk] = *reinterpret_cast<const bf16x8*>(Bp + kk * 32);

  #pragma unroll
  for (int c = 0; c < 8; ++c) {
    const int cur = c & 1;
    if (c < 7) {
      #pragma unroll
      for (int kk = 0; kk < 8; ++kk)
        bBuf[cur ^ 1][kk] = *reinterpret_cast<const bf16x8*>(Bp + (c + 1) * 256 + kk * 32);
    }
    #pragma unroll
    for (int kk = 0; kk < 8; ++kk) {
      bf16x8 a = *reinterpret_cast<const bf16x8*>(&A4[arow + c * 32 + ((kk * 4 + kg) ^ aswz)]);
      if (cur == 0) acc0 = __builtin_amdgcn_mfma_f32_16x16x32_bf16(a, bBuf[0][kk], acc0, 0, 0, 0);
      else          acc1 = __builtin_amdgcn_mfma_f32_16x16x32_bf16(a, bBuf[1][kk], acc1, 0, 0, 0);
    }
  }
  __syncthreads();   // all A reads done; overlay hp

  #pragma unroll
  for (int q = 0; q < 4; ++q) hp[kg * 4 + q][ch] = acc0[q] + acc1[q];
  __syncthreads();

  const int row = t >> 5;
  const int c0  = t & 31;
  float v[4], s = 0.f, sq = 0.f;
  #pragma unroll
  for (int e = 0; e < 4; ++e) {
    v[e] = hp[row][c0 + e * 32];
    s += v[e]; sq += v[e] * v[e];
  }
  #pragma unroll
  for (int off = 16; off; off >>= 1) { s += __shfl_xor(s, off); sq += __shfl_xor(sq, off); }
  const float mu  = s  * (1.f / 128.f);
  const float var = sq * (1.f / 128.f) - mu * mu;
  const float inv = rsqrtf(var + EPS_);
  float* orow = out0 + ((size_t)(b * N_ + i0 + row)) * OUTF_;
  #pragma unroll
  for (int e = 0; e < 4; ++e) {
    const int chh = c0 + e * 32;
    float y = (v[e] - mu) * inv * gamma[chh] + beta[chh];
    y *= OUT_SCALE_;
    orow[chh] = 0.5f * y * (1.f + erff(y * 0.70710678118654752f));
  }
}

extern "C" void kernel_launch(void* const* d_in, const int* in_sizes, int n_in,
                              void* d_out, int out_size, void* d_ws, size_t ws_size,
                              hipStream_t stream) {
  (void)in_sizes; (void)n_in; (void)out_size; (void)ws_size;
  const float* h        = (const float*)d_in[0];
  const int*   adj      = (const int*)d_in[1];
  const float* W        = (const float*)d_in[2];
  const float* alp      = (const float*)d_in[3];
  const float* arp      = (const float*)d_in[4];
  const float* aln      = (const float*)d_in[5];
  const float* arn      = (const float*)d_in[6];
  const float* rel_emb  = (const float*)d_in[7];
  const float* a_rel_p  = (const float*)d_in[8];
  const float* a_rel_n  = (const float*)d_in[9];
  const float* ll1      = (const float*)d_in[10];
  const float* lr1      = (const float*)d_in[11];
  const float* ll2      = (const float*)d_in[12];
  const float* lr2      = (const float*)d_in[13];
  const float* gamma    = (const float*)d_in[14];
  const float* beta     = (const float*)d_in[15];

  float* out0 = (float*)d_out;                          // gelu(h'): B*N*OUTF
  float* out1 = out0 + (size_t)B_ * N_ * OUTF_;         // attention: B*N*N

  float* ws    = (float*)d_ws;
  float* scal  = ws;                    // 32 floats
  float* lposv = ws + 32;               // B*N
  float* rposv = lposv + B_ * N_;
  float* lnegv = rposv + B_ * N_;
  float* rnegv = lnegv + B_ * N_;
  unsigned short* WhvT = (unsigned short*)(rnegv + B_ * N_);   // [B][OUTF][N] bf16

  wh_dots_v3<<<(B_ * N_) / 32, 256, 0, stream>>>(h, W, alp, arp, aln, arn,
                                                 rel_emb, a_rel_p, a_rel_n,
                                                 ll1, lr1, ll2, lr2,
                                                 WhvT, lposv, rposv, lnegv, rnegv, scal);
  fused_attn_pv5<<<B_ * (N_ / 16), 512, 0, stream>>>(adj, lposv, rposv, lnegv, rnegv,
                                                     scal, WhvT, gamma, beta, out0, out1);
}